// Round 5
// baseline (297.894 us; speedup 1.0000x reference)
//
#include <hip/hip_runtime.h>
#include <cmath>

#define N_NODES 50000
#define N_EDGES 800000
#define N_FEAT 128
#define DIM 64
#define N_GRAPHS 512
#define SCAN_NBLK ((N_NODES + 255) / 256)   // 196
#define EGRID ((N_EDGES + 255) / 256)       // 3125
#define GGRID ((N_NODES + 63) / 64)         // 782

// ---------------------------------------------------------------------------
__global__ __launch_bounds__(256) void zero_i(int* __restrict__ p, int n) {
  int i = blockIdx.x * 256 + threadIdx.x;
  if (i < n) p[i] = 0;
}

// CSR build: histogram of dst
__global__ __launch_bounds__(256) void hist_dst(const int* __restrict__ dst,
                                                int* __restrict__ deg) {
  int e = blockIdx.x * 256 + threadIdx.x;
  if (e < N_EDGES) atomicAdd(&deg[dst[e]], 1);
}

// hierarchical exclusive scan: deg -> row_ptr[N+1], fill_pos
__global__ __launch_bounds__(256) void partial_sums(const int* __restrict__ deg,
                                                    int* __restrict__ partials) {
  __shared__ int ws[4];
  int gid = blockIdx.x * 256 + threadIdx.x;
  int v = (gid < N_NODES) ? deg[gid] : 0;
#pragma unroll
  for (int off = 32; off; off >>= 1) v += __shfl_down(v, off, 64);
  int lane = threadIdx.x & 63, w = threadIdx.x >> 6;
  if (lane == 0) ws[w] = v;
  __syncthreads();
  if (threadIdx.x == 0)
    partials[blockIdx.x] = ws[0] + ws[1] + ws[2] + ws[3];
}

__global__ __launch_bounds__(256) void scan_partials(int* __restrict__ partials) {
  __shared__ int buf[256];
  int tid = threadIdx.x;
  int v = (tid < SCAN_NBLK) ? partials[tid] : 0;
  buf[tid] = v;
  __syncthreads();
  for (int off = 1; off < 256; off <<= 1) {
    int t = (tid >= off) ? buf[tid - off] : 0;
    __syncthreads();
    buf[tid] += t;
    __syncthreads();
  }
  if (tid < SCAN_NBLK) partials[tid] = buf[tid] - v;   // exclusive
}

__global__ __launch_bounds__(256) void scan_blocks(const int* __restrict__ deg,
                                                   const int* __restrict__ partials,
                                                   int* __restrict__ row_ptr,
                                                   int* __restrict__ fill_pos) {
  __shared__ int buf[256];
  int tid = threadIdx.x;
  int gid = blockIdx.x * 256 + tid;
  int v = (gid < N_NODES) ? deg[gid] : 0;
  buf[tid] = v;
  __syncthreads();
  for (int off = 1; off < 256; off <<= 1) {
    int t = (tid >= off) ? buf[tid - off] : 0;
    __syncthreads();
    buf[tid] += t;
    __syncthreads();
  }
  int excl = buf[tid] - v + partials[blockIdx.x];
  if (gid <= N_NODES) {
    row_ptr[gid] = excl;
    if (gid < N_NODES) fill_pos[gid] = excl;
  }
}

// ---------------------------------------------------------------------------
// GEMM body for gemm1: out[M][64] = A[M][128] @ W[128][64], chunked staging.
template<int K, bool RELU>
__device__ __forceinline__ void gemm_body(const float* __restrict__ A,
                                          const float* __restrict__ W,
                                          float* __restrict__ out, int M,
                                          int row0, int tid,
                                          float* sX, float* sW) {
  const int tx = tid & 15, ty = tid >> 4;
  const int q = tid & 7, r0 = tid >> 3;
  float acc[4][4] = {};

  for (int kb = 0; kb < K; kb += 32) {
    __syncthreads();
    if ((kb & 63) == 0) {
#pragma unroll
      for (int i = 0; i < 16; i++)
        sW[i * 256 + tid] = W[kb * 64 + i * 256 + tid];
    }
#pragma unroll
    for (int rr = 0; rr < 64; rr += 32) {
      int r = r0 + rr;
      int gr = row0 + r;
      float4 v = make_float4(0.f, 0.f, 0.f, 0.f);
      if (gr < M) v = *(const float4*)&A[(size_t)gr * K + kb + q * 4];
      if (RELU) {
        v.x = fmaxf(v.x, 0.f); v.y = fmaxf(v.y, 0.f);
        v.z = fmaxf(v.z, 0.f); v.w = fmaxf(v.w, 0.f);
      }
      *(float4*)&sX[r * 36 + q * 4] = v;
    }
    __syncthreads();

    const int kw = kb & 63;
#pragma unroll 4
    for (int k = 0; k < 32; k += 4) {
      float4 wv[4];
#pragma unroll
      for (int kk = 0; kk < 4; kk++)
        wv[kk] = *(const float4*)&sW[(kw + k + kk) * 64 + tx * 4];
#pragma unroll
      for (int r = 0; r < 4; r++) {
        float4 xv = *(const float4*)&sX[(ty * 4 + r) * 36 + k];
        const float xs[4] = {xv.x, xv.y, xv.z, xv.w};
#pragma unroll
        for (int kk = 0; kk < 4; kk++) {
          acc[r][0] += xs[kk] * wv[kk].x;
          acc[r][1] += xs[kk] * wv[kk].y;
          acc[r][2] += xs[kk] * wv[kk].z;
          acc[r][3] += xs[kk] * wv[kk].w;
        }
      }
    }
  }

#pragma unroll
  for (int r = 0; r < 4; r++) {
    int gr = row0 + ty * 4 + r;
    if (gr < M)
      *(float4*)&out[(size_t)gr * 64 + tx * 4] =
          make_float4(acc[r][0], acc[r][1], acc[r][2], acc[r][3]);
  }
}

// fused: blocks [0,GGRID) run gemm1 (x@W1 -> h1); blocks [GGRID,+EGRID) run
// fill_csr. Independent work in one dispatch overlaps the scatter.
__global__ __launch_bounds__(256) void gemm1_fill(const float* __restrict__ x,
                                                  const float* __restrict__ W1,
                                                  float* __restrict__ h1,
                                                  const int* __restrict__ src,
                                                  const int* __restrict__ dst,
                                                  int* __restrict__ fill_pos,
                                                  int* __restrict__ col) {
  __shared__ float sX[64 * 36];
  __shared__ float sW[64 * 64];
  if (blockIdx.x < GGRID) {
    gemm_body<N_FEAT, false>(x, W1, h1, N_NODES, blockIdx.x * 64, threadIdx.x, sX, sW);
  } else {
    int e = (blockIdx.x - GGRID) * 256 + threadIdx.x;
    if (e < N_EDGES) {
      int slot = atomicAdd(&fill_pos[dst[e]], 1);
      col[slot] = src[e];
    }
  }
}

// ---------------------------------------------------------------------------
// per-node gather partial: lane = (eo edge-offset 0..3, qfo feature-quad*4).
// Returns lane-partial float4 over the node's in-edges (no cross-lane reduce).
__device__ __forceinline__ float4 gather_node(const float* __restrict__ h,
                                              const int* __restrict__ col,
                                              int i, int end, int eo, int qfo,
                                              float4 acc) {
  for (; i + 8 <= end; i += 8) {
    int s0 = col[i + eo];
    int s1 = col[i + 4 + eo];
    float4 v0 = *(const float4*)&h[(size_t)s0 * 64 + qfo];
    float4 v1 = *(const float4*)&h[(size_t)s1 * 64 + qfo];
    acc.x += v0.x + v1.x; acc.y += v0.y + v1.y;
    acc.z += v0.z + v1.z; acc.w += v0.w + v1.w;
  }
  for (; i + 4 <= end; i += 4) {
    int s = col[i + eo];
    float4 v = *(const float4*)&h[(size_t)s * 64 + qfo];
    acc.x += v.x; acc.y += v.y; acc.z += v.z; acc.w += v.w;
  }
  if (eo < end - i) {
    int s = col[i + eo];
    float4 v = *(const float4*)&h[(size_t)s * 64 + qfo];
    acc.x += v.x; acc.y += v.y; acc.z += v.z; acc.w += v.w;
  }
  return acc;
}

// ---------------------------------------------------------------------------
// fused gather1 + gemm2: block = 64-node tile. 4 waves gather 16 nodes each
// straight into the LDS A-tile (relu post-reduction), then 4x4 register GEMM.
// Kills the agg write+read round-trip (25.6 MB).
__global__ __launch_bounds__(256) void gather_gemm2(
    const float* __restrict__ h1, const int* __restrict__ row_ptr,
    const int* __restrict__ col, const float* __restrict__ W2,
    float* __restrict__ h2) {
  __shared__ float sX[64 * 68];          // 64 rows x 64 k, pad +4
  __shared__ float sW[64 * 64];
  const int tid = threadIdx.x;
  const int row0 = blockIdx.x * 64;
  const int lane = tid & 63, w = tid >> 6;
  const int eo = lane >> 4, qfo = (lane & 15) << 2;

#pragma unroll
  for (int i = 0; i < 16; i++) sW[i * 256 + tid] = W2[i * 256 + tid];

  for (int ni = 0; ni < 16; ni++) {
    int node = row0 + w * 16 + ni;
    float4 acc = make_float4(0.f, 0.f, 0.f, 0.f);
    if (node < N_NODES) {
      int i0 = row_ptr[node], e0 = row_ptr[node + 1];
      acc = gather_node(h1, col, i0, e0, eo, qfo, acc);
    }
#pragma unroll
    for (int m = 16; m <= 32; m <<= 1) {
      acc.x += __shfl_xor(acc.x, m, 64);
      acc.y += __shfl_xor(acc.y, m, 64);
      acc.z += __shfl_xor(acc.z, m, 64);
      acc.w += __shfl_xor(acc.w, m, 64);
    }
    if (eo == 0) {                        // relu = gemm2's A activation
      acc.x = fmaxf(acc.x, 0.f); acc.y = fmaxf(acc.y, 0.f);
      acc.z = fmaxf(acc.z, 0.f); acc.w = fmaxf(acc.w, 0.f);
      *(float4*)&sX[(w * 16 + ni) * 68 + qfo] = acc;
    }
  }
  __syncthreads();

  const int tx = tid & 15, ty = tid >> 4;
  float acc[4][4] = {};
#pragma unroll 4
  for (int k = 0; k < 64; k += 4) {
    float4 wv[4];
#pragma unroll
    for (int kk = 0; kk < 4; kk++)
      wv[kk] = *(const float4*)&sW[(k + kk) * 64 + tx * 4];
#pragma unroll
    for (int r = 0; r < 4; r++) {
      float4 xv = *(const float4*)&sX[(ty * 4 + r) * 68 + k];
      const float xs[4] = {xv.x, xv.y, xv.z, xv.w};
#pragma unroll
      for (int kk = 0; kk < 4; kk++) {
        acc[r][0] += xs[kk] * wv[kk].x;
        acc[r][1] += xs[kk] * wv[kk].y;
        acc[r][2] += xs[kk] * wv[kk].z;
        acc[r][3] += xs[kk] * wv[kk].w;
      }
    }
  }
#pragma unroll
  for (int r = 0; r < 4; r++) {
    int gr = row0 + ty * 4 + r;
    if (gr < N_NODES)
      *(float4*)&h2[(size_t)gr * 64 + tx * 4] =
          make_float4(acc[r][0], acc[r][1], acc[r][2], acc[r][3]);
  }
}

// ---------------------------------------------------------------------------
// fused gather2 + mean-pool + FC + sigmoid: block = graph. Pool sums every
// aggregated row, so agg2 never materializes — waves accumulate gathered
// rows straight into pooled registers. Writes only out[512].
__global__ __launch_bounds__(256) void gather_pool_fc(
    const float* __restrict__ h2, const int* __restrict__ row_ptr,
    const int* __restrict__ col, const int* __restrict__ batch,
    const float* __restrict__ Wfc, float* __restrict__ out) {
  __shared__ float sacc[4][64];
  int g = blockIdx.x;
  int tid = threadIdx.x, lane = tid & 63, w = tid >> 6;
  int eo = lane >> 4, qfo = (lane & 15) << 2;

  int lo = 0, hi = N_NODES;
  while (lo < hi) { int mid = (lo + hi) >> 1; if (batch[mid] < g) lo = mid + 1; else hi = mid; }
  const int start = lo;
  hi = N_NODES;
  while (lo < hi) { int mid = (lo + hi) >> 1; if (batch[mid] < g + 1) lo = mid + 1; else hi = mid; }
  const int end = lo;

  float4 acc = make_float4(0.f, 0.f, 0.f, 0.f);
  for (int n = start + w; n < end; n += 4) {
    int i0 = row_ptr[n], e0 = row_ptr[n + 1];
    acc = gather_node(h2, col, i0, e0, eo, qfo, acc);
  }
#pragma unroll
  for (int m = 16; m <= 32; m <<= 1) {
    acc.x += __shfl_xor(acc.x, m, 64);
    acc.y += __shfl_xor(acc.y, m, 64);
    acc.z += __shfl_xor(acc.z, m, 64);
    acc.w += __shfl_xor(acc.w, m, 64);
  }
  if (eo == 0) *(float4*)&sacc[w][qfo] = acc;
  __syncthreads();

  if (w == 0) {
    float v = sacc[0][lane] + sacc[1][lane] + sacc[2][lane] + sacc[3][lane];
    v /= fmaxf((float)(end - start), 1.f);
    v *= Wfc[lane];
#pragma unroll
    for (int off = 32; off; off >>= 1) v += __shfl_down(v, off, 64);
    if (lane == 0) out[g] = 1.f / (1.f + expf(-v));
  }
}

// ---------------------------------------------------------------------------
extern "C" void kernel_launch(void* const* d_in, const int* in_sizes, int n_in,
                              void* d_out, int out_size, void* d_ws, size_t ws_size,
                              hipStream_t stream) {
  const float* x     = (const float*)d_in[0];
  const int*   ei    = (const int*)d_in[1];   // [2, E]: src then dst
  const int*   batch = (const int*)d_in[2];
  const float* W1    = (const float*)d_in[3];
  const float* W2    = (const float*)d_in[4];
  const float* Wfc   = (const float*)d_in[5];
  float*       out   = (float*)d_out;

  const int* src = ei;
  const int* dst = ei + N_EDGES;

  // workspace layout (~29.4 MB)
  char* ws = (char*)d_ws;
  float* h1       = (float*)(ws);                                   // [N,64]
  float* h2       = (float*)(ws + (size_t)N_NODES * DIM * 4);       // [N,64]
  int*   deg      = (int*)  (ws + (size_t)N_NODES * DIM * 8);
  int*   row_ptr  = deg + N_NODES;
  int*   fill_pos = row_ptr + N_NODES + 1;
  int*   col      = fill_pos + N_NODES;                             // [E]
  int*   partials = col + N_EDGES;                                  // [196]

  // CSR build front half (shared by both layers)
  zero_i<<<SCAN_NBLK, 256, 0, stream>>>(deg, N_NODES);
  hist_dst<<<EGRID, 256, 0, stream>>>(dst, deg);
  partial_sums<<<SCAN_NBLK, 256, 0, stream>>>(deg, partials);
  scan_partials<<<1, 256, 0, stream>>>(partials);
  scan_blocks<<<SCAN_NBLK, 256, 0, stream>>>(deg, partials, row_ptr, fill_pos);

  // fill_csr || gemm1: h1 = x @ W1, col[] built
  gemm1_fill<<<GGRID + EGRID, 256, 0, stream>>>(x, W1, h1, src, dst, fill_pos, col);

  // layer 1 aggregate + relu + gemm2 (fused): h2 = relu(agg1) @ W2
  gather_gemm2<<<GGRID, 256, 0, stream>>>(h1, row_ptr, col, W2, h2);

  // layer 2 aggregate + mean-pool + FC + sigmoid (fused)
  gather_pool_fc<<<N_GRAPHS, 256, 0, stream>>>(h2, row_ptr, col, batch, Wfc, out);
}

// Round 6
// 265.385 us; speedup vs baseline: 1.1225x; 1.1225x over previous
//
#include <hip/hip_runtime.h>
#include <cmath>

#define N_NODES 50000
#define N_EDGES 800000
#define N_FEAT 128
#define DIM 64
#define N_GRAPHS 512
#define SCAN_NBLK ((N_NODES + 255) / 256)   // 196
#define EGRID ((N_EDGES + 255) / 256)       // 3125
#define GGRID ((N_NODES + 63) / 64)         // 782

// bf16 storage helpers (RNE). Storage-only: all math in fp32.
__device__ __forceinline__ unsigned short f2bf(float f) {
  union { float f; unsigned int u; } v; v.f = f;
  return (unsigned short)((v.u + 0x7FFFu + ((v.u >> 16) & 1u)) >> 16);
}
__device__ __forceinline__ float bf2f(unsigned short u) {
  union { unsigned int u; float f; } v; v.u = (unsigned int)u << 16;
  return v.f;
}

// ---------------------------------------------------------------------------
__global__ __launch_bounds__(256) void zero_i(int* __restrict__ p, int n) {
  int i = blockIdx.x * 256 + threadIdx.x;
  if (i < n) p[i] = 0;
}

// CSR build: histogram of dst
__global__ __launch_bounds__(256) void hist_dst(const int* __restrict__ dst,
                                                int* __restrict__ deg) {
  int e = blockIdx.x * 256 + threadIdx.x;
  if (e < N_EDGES) atomicAdd(&deg[dst[e]], 1);
}

// hierarchical exclusive scan: deg -> row_ptr[N+1], fill_pos
__global__ __launch_bounds__(256) void partial_sums(const int* __restrict__ deg,
                                                    int* __restrict__ partials) {
  __shared__ int ws[4];
  int gid = blockIdx.x * 256 + threadIdx.x;
  int v = (gid < N_NODES) ? deg[gid] : 0;
#pragma unroll
  for (int off = 32; off; off >>= 1) v += __shfl_down(v, off, 64);
  int lane = threadIdx.x & 63, w = threadIdx.x >> 6;
  if (lane == 0) ws[w] = v;
  __syncthreads();
  if (threadIdx.x == 0)
    partials[blockIdx.x] = ws[0] + ws[1] + ws[2] + ws[3];
}

__global__ __launch_bounds__(256) void scan_partials(int* __restrict__ partials) {
  __shared__ int buf[256];
  int tid = threadIdx.x;
  int v = (tid < SCAN_NBLK) ? partials[tid] : 0;
  buf[tid] = v;
  __syncthreads();
  for (int off = 1; off < 256; off <<= 1) {
    int t = (tid >= off) ? buf[tid - off] : 0;
    __syncthreads();
    buf[tid] += t;
    __syncthreads();
  }
  if (tid < SCAN_NBLK) partials[tid] = buf[tid] - v;   // exclusive
}

__global__ __launch_bounds__(256) void scan_blocks(const int* __restrict__ deg,
                                                   const int* __restrict__ partials,
                                                   int* __restrict__ row_ptr,
                                                   int* __restrict__ fill_pos) {
  __shared__ int buf[256];
  int tid = threadIdx.x;
  int gid = blockIdx.x * 256 + tid;
  int v = (gid < N_NODES) ? deg[gid] : 0;
  buf[tid] = v;
  __syncthreads();
  for (int off = 1; off < 256; off <<= 1) {
    int t = (tid >= off) ? buf[tid - off] : 0;
    __syncthreads();
    buf[tid] += t;
    __syncthreads();
  }
  int excl = buf[tid] - v + partials[blockIdx.x];
  if (gid <= N_NODES) {
    row_ptr[gid] = excl;
    if (gid < N_NODES) fill_pos[gid] = excl;
  }
}

// ---------------------------------------------------------------------------
// GEMM body for gemm1: out[M][64] = A[M][128] @ W[128][64], bf16 output rows.
template<int K>
__device__ __forceinline__ void gemm_body_bf(const float* __restrict__ A,
                                             const float* __restrict__ W,
                                             unsigned short* __restrict__ out,
                                             int M, int row0, int tid,
                                             float* sX, float* sW) {
  const int tx = tid & 15, ty = tid >> 4;
  const int q = tid & 7, r0 = tid >> 3;
  float acc[4][4] = {};

  for (int kb = 0; kb < K; kb += 32) {
    __syncthreads();
    if ((kb & 63) == 0) {
#pragma unroll
      for (int i = 0; i < 16; i++)
        sW[i * 256 + tid] = W[kb * 64 + i * 256 + tid];
    }
#pragma unroll
    for (int rr = 0; rr < 64; rr += 32) {
      int r = r0 + rr;
      int gr = row0 + r;
      float4 v = make_float4(0.f, 0.f, 0.f, 0.f);
      if (gr < M) v = *(const float4*)&A[(size_t)gr * K + kb + q * 4];
      *(float4*)&sX[r * 36 + q * 4] = v;
    }
    __syncthreads();

    const int kw = kb & 63;
#pragma unroll 4
    for (int k = 0; k < 32; k += 4) {
      float4 wv[4];
#pragma unroll
      for (int kk = 0; kk < 4; kk++)
        wv[kk] = *(const float4*)&sW[(kw + k + kk) * 64 + tx * 4];
#pragma unroll
      for (int r = 0; r < 4; r++) {
        float4 xv = *(const float4*)&sX[(ty * 4 + r) * 36 + k];
        const float xs[4] = {xv.x, xv.y, xv.z, xv.w};
#pragma unroll
        for (int kk = 0; kk < 4; kk++) {
          acc[r][0] += xs[kk] * wv[kk].x;
          acc[r][1] += xs[kk] * wv[kk].y;
          acc[r][2] += xs[kk] * wv[kk].z;
          acc[r][3] += xs[kk] * wv[kk].w;
        }
      }
    }
  }

#pragma unroll
  for (int r = 0; r < 4; r++) {
    int gr = row0 + ty * 4 + r;
    if (gr < M) {
      ushort4 u;
      u.x = f2bf(acc[r][0]); u.y = f2bf(acc[r][1]);
      u.z = f2bf(acc[r][2]); u.w = f2bf(acc[r][3]);
      *(ushort4*)&out[(size_t)gr * 64 + tx * 4] = u;
    }
  }
}

// fused: blocks [0,GGRID) run gemm1 (x@W1 -> h1 bf16); rest run fill_csr.
__global__ __launch_bounds__(256) void gemm1_fill(const float* __restrict__ x,
                                                  const float* __restrict__ W1,
                                                  unsigned short* __restrict__ h1,
                                                  const int* __restrict__ src,
                                                  const int* __restrict__ dst,
                                                  int* __restrict__ fill_pos,
                                                  int* __restrict__ col) {
  __shared__ float sX[64 * 36];
  __shared__ float sW[64 * 64];
  if (blockIdx.x < GGRID) {
    gemm_body_bf<N_FEAT>(x, W1, h1, N_NODES, blockIdx.x * 64, threadIdx.x, sX, sW);
  } else {
    int e = (blockIdx.x - GGRID) * 256 + threadIdx.x;
    if (e < N_EDGES) {
      int slot = atomicAdd(&fill_pos[dst[e]], 1);
      col[slot] = src[e];
    }
  }
}

// ---------------------------------------------------------------------------
// per-node gather partial over bf16 rows: lane = (eo 0..3, qfo quad*4).
// 16 lanes x ushort4 (8B) = one 128B coalesced row per edge.
__device__ __forceinline__ float4 gather_node_bf(const unsigned short* __restrict__ h,
                                                 const int* __restrict__ col,
                                                 int i, int end, int eo, int qfo,
                                                 float4 acc) {
  for (; i + 8 <= end; i += 8) {
    int s0 = col[i + eo];
    int s1 = col[i + 4 + eo];
    ushort4 u0 = *(const ushort4*)&h[(size_t)s0 * 64 + qfo];
    ushort4 u1 = *(const ushort4*)&h[(size_t)s1 * 64 + qfo];
    acc.x += bf2f(u0.x) + bf2f(u1.x);
    acc.y += bf2f(u0.y) + bf2f(u1.y);
    acc.z += bf2f(u0.z) + bf2f(u1.z);
    acc.w += bf2f(u0.w) + bf2f(u1.w);
  }
  for (; i + 4 <= end; i += 4) {
    int s = col[i + eo];
    ushort4 u = *(const ushort4*)&h[(size_t)s * 64 + qfo];
    acc.x += bf2f(u.x); acc.y += bf2f(u.y);
    acc.z += bf2f(u.z); acc.w += bf2f(u.w);
  }
  if (eo < end - i) {
    int s = col[i + eo];
    ushort4 u = *(const ushort4*)&h[(size_t)s * 64 + qfo];
    acc.x += bf2f(u.x); acc.y += bf2f(u.y);
    acc.z += bf2f(u.z); acc.w += bf2f(u.w);
  }
  return acc;
}

// ---------------------------------------------------------------------------
// fused gather1 + gemm2: block = 64-node tile. 4 waves gather 16 nodes each
// into the LDS A-tile (relu post-reduction), then 4x4 register GEMM. h2 bf16.
__global__ __launch_bounds__(256) void gather_gemm2(
    const unsigned short* __restrict__ h1, const int* __restrict__ row_ptr,
    const int* __restrict__ col, const float* __restrict__ W2,
    unsigned short* __restrict__ h2) {
  __shared__ float sX[64 * 68];          // 64 rows x 64 k, pad +4
  __shared__ float sW[64 * 64];
  const int tid = threadIdx.x;
  const int row0 = blockIdx.x * 64;
  const int lane = tid & 63, w = tid >> 6;
  const int eo = lane >> 4, qfo = (lane & 15) << 2;

#pragma unroll
  for (int i = 0; i < 16; i++) sW[i * 256 + tid] = W2[i * 256 + tid];

  for (int ni = 0; ni < 16; ni++) {
    int node = row0 + w * 16 + ni;
    float4 acc = make_float4(0.f, 0.f, 0.f, 0.f);
    if (node < N_NODES) {
      int i0 = row_ptr[node], e0 = row_ptr[node + 1];
      acc = gather_node_bf(h1, col, i0, e0, eo, qfo, acc);
    }
#pragma unroll
    for (int m = 16; m <= 32; m <<= 1) {
      acc.x += __shfl_xor(acc.x, m, 64);
      acc.y += __shfl_xor(acc.y, m, 64);
      acc.z += __shfl_xor(acc.z, m, 64);
      acc.w += __shfl_xor(acc.w, m, 64);
    }
    if (eo == 0) {                        // relu = layer-1 activation
      acc.x = fmaxf(acc.x, 0.f); acc.y = fmaxf(acc.y, 0.f);
      acc.z = fmaxf(acc.z, 0.f); acc.w = fmaxf(acc.w, 0.f);
      *(float4*)&sX[(w * 16 + ni) * 68 + qfo] = acc;
    }
  }
  __syncthreads();

  const int tx = tid & 15, ty = tid >> 4;
  float acc[4][4] = {};
#pragma unroll 4
  for (int k = 0; k < 64; k += 4) {
    float4 wv[4];
#pragma unroll
    for (int kk = 0; kk < 4; kk++)
      wv[kk] = *(const float4*)&sW[(k + kk) * 64 + tx * 4];
#pragma unroll
    for (int r = 0; r < 4; r++) {
      float4 xv = *(const float4*)&sX[(ty * 4 + r) * 68 + k];
      const float xs[4] = {xv.x, xv.y, xv.z, xv.w};
#pragma unroll
      for (int kk = 0; kk < 4; kk++) {
        acc[r][0] += xs[kk] * wv[kk].x;
        acc[r][1] += xs[kk] * wv[kk].y;
        acc[r][2] += xs[kk] * wv[kk].z;
        acc[r][3] += xs[kk] * wv[kk].w;
      }
    }
  }
#pragma unroll
  for (int r = 0; r < 4; r++) {
    int gr = row0 + ty * 4 + r;
    if (gr < N_NODES) {
      ushort4 u;
      u.x = f2bf(acc[r][0]); u.y = f2bf(acc[r][1]);
      u.z = f2bf(acc[r][2]); u.w = f2bf(acc[r][3]);
      *(ushort4*)&h2[(size_t)gr * 64 + tx * 4] = u;
    }
  }
}

// ---------------------------------------------------------------------------
// layer-2 aggregate, node-parallel (12500 blocks — latency hiding for the
// random-row gather). agg fp32 for the pool.
__global__ __launch_bounds__(256) void gather_sum(const unsigned short* __restrict__ h,
                                                  const int* __restrict__ row_ptr,
                                                  const int* __restrict__ col,
                                                  float* __restrict__ out) {
  int node = blockIdx.x * 4 + (threadIdx.x >> 6);
  if (node >= N_NODES) return;
  int lane = threadIdx.x & 63;
  int eo = lane >> 4, qfo = (lane & 15) << 2;
  int i = row_ptr[node];
  const int end = row_ptr[node + 1];

  float4 acc = gather_node_bf(h, col, i, end, eo, qfo,
                              make_float4(0.f, 0.f, 0.f, 0.f));
#pragma unroll
  for (int m = 16; m <= 32; m <<= 1) {
    acc.x += __shfl_xor(acc.x, m, 64);
    acc.y += __shfl_xor(acc.y, m, 64);
    acc.z += __shfl_xor(acc.z, m, 64);
    acc.w += __shfl_xor(acc.w, m, 64);
  }
  if (eo == 0) *(float4*)&out[(size_t)node * 64 + qfo] = acc;
}

// ---------------------------------------------------------------------------
// batch is SORTED -> contiguous segment per graph. 4 waves split the rows.
__global__ __launch_bounds__(256) void pool_fc(const float* __restrict__ agg,
                                               const int* __restrict__ batch,
                                               const float* __restrict__ Wfc,
                                               float* __restrict__ out) {
  __shared__ float sacc[4][64];
  int g = blockIdx.x;
  int tid = threadIdx.x, lane = tid & 63, w = tid >> 6;

  int lo = 0, hi = N_NODES;
  while (lo < hi) { int mid = (lo + hi) >> 1; if (batch[mid] < g) lo = mid + 1; else hi = mid; }
  const int start = lo;
  hi = N_NODES;
  while (lo < hi) { int mid = (lo + hi) >> 1; if (batch[mid] < g + 1) lo = mid + 1; else hi = mid; }
  const int end = lo;

  float acc = 0.f;
  for (int n = start + w; n < end; n += 4) acc += agg[(size_t)n * 64 + lane];
  sacc[w][lane] = acc;
  __syncthreads();
  if (w == 0) {
    float v = sacc[0][lane] + sacc[1][lane] + sacc[2][lane] + sacc[3][lane];
    v /= fmaxf((float)(end - start), 1.f);
    v *= Wfc[lane];
#pragma unroll
    for (int off = 32; off; off >>= 1) v += __shfl_down(v, off, 64);
    if (lane == 0) out[g] = 1.f / (1.f + expf(-v));
  }
}

// ---------------------------------------------------------------------------
extern "C" void kernel_launch(void* const* d_in, const int* in_sizes, int n_in,
                              void* d_out, int out_size, void* d_ws, size_t ws_size,
                              hipStream_t stream) {
  const float* x     = (const float*)d_in[0];
  const int*   ei    = (const int*)d_in[1];   // [2, E]: src then dst
  const int*   batch = (const int*)d_in[2];
  const float* W1    = (const float*)d_in[3];
  const float* W2    = (const float*)d_in[4];
  const float* Wfc   = (const float*)d_in[5];
  float*       out   = (float*)d_out;

  const int* src = ei;
  const int* dst = ei + N_EDGES;

  // workspace layout (~29.4 MB)
  char* ws = (char*)d_ws;
  unsigned short* h1 = (unsigned short*)(ws);                         // [N,64] bf16
  unsigned short* h2 = h1 + (size_t)N_NODES * DIM;                    // [N,64] bf16
  float* agg      = (float*)(ws + (size_t)N_NODES * DIM * 4);         // [N,64] fp32
  int*   deg      = (int*)  (ws + (size_t)N_NODES * DIM * 8);
  int*   row_ptr  = deg + N_NODES;
  int*   fill_pos = row_ptr + N_NODES + 1;
  int*   col      = fill_pos + N_NODES;                               // [E]
  int*   partials = col + N_EDGES;                                    // [196]

  const int ngrid4 = (N_NODES + 3) / 4;

  // CSR build front half (shared by both layers)
  zero_i<<<SCAN_NBLK, 256, 0, stream>>>(deg, N_NODES);
  hist_dst<<<EGRID, 256, 0, stream>>>(dst, deg);
  partial_sums<<<SCAN_NBLK, 256, 0, stream>>>(deg, partials);
  scan_partials<<<1, 256, 0, stream>>>(partials);
  scan_blocks<<<SCAN_NBLK, 256, 0, stream>>>(deg, partials, row_ptr, fill_pos);

  // fill_csr || gemm1: h1 = bf16(x @ W1), col[] built
  gemm1_fill<<<GGRID + EGRID, 256, 0, stream>>>(x, W1, h1, src, dst, fill_pos, col);

  // layer 1 aggregate + relu + gemm2 (fused): h2 = bf16(relu(agg1) @ W2)
  gather_gemm2<<<GGRID, 256, 0, stream>>>(h1, row_ptr, col, W2, h2);

  // layer 2 aggregate (node-parallel), then mean-pool + FC + sigmoid
  gather_sum<<<ngrid4, 256, 0, stream>>>(h2, row_ptr, col, agg);
  pool_fc<<<N_GRAPHS, 256, 0, stream>>>(agg, batch, Wfc, out);
}